// Round 6
// baseline (1966.367 us; speedup 1.0000x reference)
//
#include <hip/hip_runtime.h>
#include <hip/hip_bf16.h>

#define NSEQ 49
#define DIMC 192
#define NHEAD 6
#define NWIN 1024
#define NBLK 8192
#define NN 2401      // 49*49
#define QSCALE 0.17677669529663687f

typedef __bf16 bf16x8 __attribute__((ext_vector_type(8)));
typedef float f32x4 __attribute__((ext_vector_type(4)));
typedef unsigned int u32x4 __attribute__((ext_vector_type(4)));
typedef unsigned short u16;

// workspace byte offsets
#define WQ_OFF 0          // bf16 [576][192]  (q rows pre-scaled)
#define WP_OFF 221184     // bf16 [192][192]
#define BIAS_OFF 294912   // f32  [6][49][49]
#define QB_OFF 352544     // f32  [576] (q part pre-scaled)
#define PB_OFF 354848     // f32  [192]

__device__ __forceinline__ u16 f2bf(float f) {
  unsigned int u = __builtin_bit_cast(unsigned int, f);
  u += 0x7fffu + ((u >> 16) & 1u);   // RNE
  return (u16)(u >> 16);
}
__device__ __forceinline__ f32x4 mfma16(bf16x8 a, bf16x8 b, f32x4 c) {
  return __builtin_amdgcn_mfma_f32_16x16x32_bf16(a, b, c, 0, 0, 0);
}
__device__ __forceinline__ f32x4 ld4u(const float* p) {
  f32x4 v; __builtin_memcpy(&v, p, 16); return v;
}
// native bf16 convert (v_cvt_pk_bf16_f32, RNE) — cheaper than manual RNE
__device__ __forceinline__ unsigned pkbf2(float lo, float hi) {
  __bf16 a = (__bf16)lo, b = (__bf16)hi;
  return (unsigned)__builtin_bit_cast(u16, a) | ((unsigned)__builtin_bit_cast(u16, b) << 16);
}
__device__ __forceinline__ void st_bf(char* p, float f) {
  *(__bf16*)p = (__bf16)f;
}
__device__ __forceinline__ bf16x8 pack8f(f32x4 a, f32x4 b) {
  u32x4 w;
  w[0] = pkbf2(a[0], a[1]);
  w[1] = pkbf2(a[2], a[3]);
  w[2] = pkbf2(b[0], b[1]);
  w[3] = pkbf2(b[2], b[3]);
  return __builtin_bit_cast(bf16x8, w);
}

__global__ void prep_kernel(const float* __restrict__ qkv_w, const float* __restrict__ qkv_b,
                            const float* __restrict__ proj_w, const float* __restrict__ proj_b,
                            const float* __restrict__ table, const int* __restrict__ ridx,
                            char* __restrict__ ws) {
  u16* wq = (u16*)(ws + WQ_OFF);
  u16* wp = (u16*)(ws + WP_OFF);
  float* biasf = (float*)(ws + BIAS_OFF);
  float* qb = (float*)(ws + QB_OFF);
  float* pb = (float*)(ws + PB_OFF);
  int idx = blockIdx.x * blockDim.x + threadIdx.x;
  const int T0 = 576*192, T1 = T0 + 192*192, T2 = T1 + NHEAD*NN, T3 = T2 + 576, T4 = T3 + 192;
  if (idx < T0) {
    float f = qkv_w[idx];
    if (idx < 192*192) f *= QSCALE;
    wq[idx] = f2bf(f);
  } else if (idx < T1) {
    int i = idx - T0;
    wp[i] = f2bf(proj_w[i]);
  } else if (idx < T2) {
    int i = idx - T1;
    int h = i / NN, rc = i - h*NN;
    biasf[i] = table[ridx[rc]*NHEAD + h];
  } else if (idx < T3) {
    int i = idx - T2;
    qb[i] = qkv_b[i] * (i < 192 ? QSCALE : 1.0f);
  } else if (idx < T4) {
    int i = idx - T3;
    pb[i] = proj_b[i];
  }
}

// LDS 49152 B -> 3 blocks/CU (with VGPR<=102 -> 18 waves/CU).
// qkb: [64 rows][768 B]: bytes [0,384) = q cols (later O), bytes [384,768) = k cols
//      (later V^T overlay, layout [d=192][seq=64 u16], base(d) = (d&63)*768+384+(d>>6)*128)
// XOR swizzle everywhere: byte_in_unit ^= (row&7)<<4
// Every LDS write-phase -> read-phase handoff crosses a __syncthreads (4 total).
__global__ __launch_bounds__(384, 5)
void wattn_kernel(const float* __restrict__ x, const float* __restrict__ mask,
                  const char* __restrict__ ws, float* __restrict__ out) {
  __shared__ __align__(16) char qkb[49152];

  const u16* wq = (const u16*)(ws + WQ_OFF);
  const u16* wp = (const u16*)(ws + WP_OFF);
  const float* biasf = (const float*)(ws + BIAS_OFF);
  const float* qb = (const float*)(ws + QB_OFF);
  const float* pb = (const float*)(ws + PB_OFF);

  const int tid = threadIdx.x;
  const int wave = tid >> 6;        // 0..5 == head
  const int lane = tid & 63;
  const int lhi = lane >> 4, llo = lane & 15;
  const int win = blockIdx.x;
  const int h = wave;

  // ---- GEMM1 in two row-halves (keeps x-tile at 48 VGPR) ----
  unsigned vp[2][2][2][2];   // [half][chunk][r2][pair] packed bf16 V (seq-pairs)
  #pragma unroll
  for (int half = 0; half < 2; ++half) {
    bf16x8 xa[2][6];
    {
      const float* xp = x + (size_t)win * (NSEQ*DIMC);
      #pragma unroll
      for (int r2 = 0; r2 < 2; ++r2) {
        int row = (half*2 + r2)*16 + llo;
        bool valid = (row < NSEQ);
        const float* pr = xp + row*DIMC + lhi*8;
        #pragma unroll
        for (int kk = 0; kk < 6; ++kk) {
          f32x4 f0 = {0.f,0.f,0.f,0.f}, f1 = {0.f,0.f,0.f,0.f};
          if (valid) { f0 = *(const f32x4*)(pr + kk*32); f1 = *(const f32x4*)(pr + kk*32 + 4); }
          xa[r2][kk] = pack8f(f0, f1);
        }
      }
    }
    #pragma unroll
    for (int cc = 0; cc < 6; ++cc) {
      int s = (cc < 2) ? (h*2 + cc)
            : (cc < 4) ? (12 + h*2 + (cc - 2))
                       : (24 + h*2 + (cc - 4));
      const u16* wrow = wq + (s*16 + llo)*DIMC + lhi*8;
      bf16x8 b0 = *(const bf16x8*)(wrow +   0);
      bf16x8 b1 = *(const bf16x8*)(wrow +  32);
      bf16x8 b2 = *(const bf16x8*)(wrow +  64);
      bf16x8 b3 = *(const bf16x8*)(wrow +  96);
      bf16x8 b4 = *(const bf16x8*)(wrow + 128);
      bf16x8 b5 = *(const bf16x8*)(wrow + 160);
      float bn = qb[s*16 + llo];
      #pragma unroll
      for (int r2 = 0; r2 < 2; ++r2) {
        f32x4 acc = {0.f,0.f,0.f,0.f};
        acc = mfma16(xa[r2][0], b0, acc);
        acc = mfma16(xa[r2][1], b1, acc);
        acc = mfma16(xa[r2][2], b2, acc);
        acc = mfma16(xa[r2][3], b3, acc);
        acc = mfma16(xa[r2][4], b4, acc);
        acc = mfma16(xa[r2][5], b5, acc);
        int rt = half*2 + r2;
        if (cc < 4) {
          int col = s*16 + llo;          // q: 0..191, k: 192..383
          #pragma unroll
          for (int i = 0; i < 4; ++i) {
            int row = rt*16 + lhi*4 + i;
            st_bf(qkb + row*768 + ((col*2) ^ ((row&7)<<4)), acc[i] + bn);
          }
        } else {
          int c = cc - 4;
          vp[half][c][r2][0] = pkbf2(acc[0] + bn, acc[1] + bn);
          vp[half][c][r2][1] = pkbf2(acc[2] + bn, acc[3] + bn);
        }
      }
    }
  }

  __syncthreads();   // B1: q/k LDS writes ordered before fragment reads

  // ---- K/Q fragment loads (swapped-T layout) ----
  bf16x8 kf[4], qf[4];
  #pragma unroll
  for (int tt = 0; tt < 4; ++tt) {
    int row = tt*16 + llo;
    kf[tt] = *(const bf16x8*)(qkb + row*768 + ((((192 + h*32)*2) + lhi*16) ^ ((row&7)<<4)));
    qf[tt] = *(const bf16x8*)(qkb + row*768 + ((((h*32)*2) + lhi*16) ^ ((row&7)<<4)));
  }

  __syncthreads();   // B2: all q/k reads done -> k region may be overlaid by V, q by O

  // ---- V -> k-region overlay, layout [d][seq] ----
  #pragma unroll
  for (int c = 0; c < 2; ++c) {
    int d = (2*h + c)*16 + llo;
    char* vb = qkb + (d&63)*768 + 384 + (d>>6)*128;
    int sw = (d&7)<<4;
    #pragma unroll
    for (int half = 0; half < 2; ++half)
      #pragma unroll
      for (int r2 = 0; r2 < 2; ++r2) {
        int seq0 = (half*2 + r2)*16 + lhi*4;
        *(unsigned*)(vb + ((seq0*2)     ^ sw)) = vp[half][c][r2][0];
        *(unsigned*)(vb + ((seq0*2 + 4) ^ sw)) = vp[half][c][r2][1];
      }
  }

  // ---- T = K·Q^T per qt, +bias+mask, softmax, pack P (t live-range = 16 regs) ----
  unsigned pk[4][4][2];   // [kt][qt][pair]
  {
    const float* brow = biasf + h*NN;
    const float* mrow = mask + (size_t)(win & (NWIN-1))*NN;
    #pragma unroll
    for (int qt = 0; qt < 4; ++qt) {
      f32x4 tq[4];
      #pragma unroll
      for (int kt = 0; kt < 4; ++kt) {
        f32x4 z = {0.f,0.f,0.f,0.f};
        tq[kt] = mfma16(kf[kt], qf[qt], z);
      }
      int q = qt*16 + llo;
      if (q < NSEQ) {
        #pragma unroll
        for (int kt = 0; kt < 3; ++kt) {
          int kb = kt*16 + lhi*4;
          f32x4 b4 = ld4u(brow + q*NSEQ + kb);
          f32x4 m4 = ld4u(mrow + q*NSEQ + kb);
          #pragma unroll
          for (int i = 0; i < 4; ++i) tq[kt][i] += b4[i] + m4[i];
        }
        if (lhi == 0) tq[3][0] += brow[q*NSEQ + 48] + mrow[q*NSEQ + 48];
      }
      float m = -1e30f;
      #pragma unroll
      for (int kt = 0; kt < 3; ++kt)
        #pragma unroll
        for (int i = 0; i < 4; ++i) m = fmaxf(m, tq[kt][i]);
      if (lhi == 0) m = fmaxf(m, tq[3][0]);
      m = fmaxf(m, __shfl_xor(m, 16));
      m = fmaxf(m, __shfl_xor(m, 32));
      float sum = 0.f;
      #pragma unroll
      for (int kt = 0; kt < 3; ++kt)
        #pragma unroll
        for (int i = 0; i < 4; ++i) { float e = __expf(tq[kt][i] - m); tq[kt][i] = e; sum += e; }
      { float e = (lhi == 0) ? __expf(tq[3][0] - m) : 0.f; tq[3][0] = e; sum += e; }
      tq[3][1] = 0.f; tq[3][2] = 0.f; tq[3][3] = 0.f;
      sum += __shfl_xor(sum, 16);
      sum += __shfl_xor(sum, 32);
      float inv = 1.f / sum;
      #pragma unroll
      for (int kt = 0; kt < 4; ++kt) {
        pk[kt][qt][0] = pkbf2(tq[kt][0]*inv, tq[kt][1]*inv);
        pk[kt][qt][1] = pkbf2(tq[kt][2]*inv, tq[kt][3]*inv);
      }
    }
  }

  __syncthreads();   // B3: V overlay visible before PV reads

  // ---- PV: O = P·V ----
  f32x4 o[4][2];
  #pragma unroll
  for (int qt = 0; qt < 4; ++qt)
    #pragma unroll
    for (int dt = 0; dt < 2; ++dt) o[qt][dt] = (f32x4){0.f,0.f,0.f,0.f};
  #pragma unroll
  for (int kk = 0; kk < 2; ++kk) {
    bf16x8 pa[4];
    #pragma unroll
    for (int qt = 0; qt < 4; ++qt) {
      u32x4 w;
      #pragma unroll
      for (int ee = 0; ee < 4; ++ee) {
        int src = (((lhi & 1)*2 + (ee >> 1)) << 4) + llo;
        int wA = __shfl((int)pk[2*kk    ][qt][ee & 1], src);
        int wB = __shfl((int)pk[2*kk + 1][qt][ee & 1], src);
        w[ee] = (lhi < 2) ? (unsigned)wA : (unsigned)wB;
      }
      pa[qt] = __builtin_bit_cast(bf16x8, w);
    }
    #pragma unroll
    for (int dt = 0; dt < 2; ++dt) {
      int dg = h*32 + dt*16 + llo;
      bf16x8 vf = *(const bf16x8*)(qkb + (dg&63)*768 + 384 + ((dg>>6)*128)
                                   + ((kk*64 + lhi*16) ^ ((dg&7)<<4)));
      #pragma unroll
      for (int qt = 0; qt < 4; ++qt) o[qt][dt] = mfma16(pa[qt], vf, o[qt][dt]);
    }
  }

  // ---- write O into own dead q-columns ----
  #pragma unroll
  for (int qt = 0; qt < 4; ++qt)
    #pragma unroll
    for (int dt = 0; dt < 2; ++dt)
      #pragma unroll
      for (int i = 0; i < 4; ++i) {
        int row = qt*16 + lhi*4 + i;
        int col = h*32 + dt*16 + llo;
        st_bf(qkb + row*768 + ((col*2) ^ ((row&7)<<4)), o[qt][dt][i]);
      }

  __syncthreads();   // B4: O complete across heads before proj

  // ---- proj: out = O @ Wp^T + pb ----
  #pragma unroll
  for (int ss = 0; ss < 2; ++ss) {
    int s = wave + ss*6;
    const u16* wrow = wp + (s*16 + llo)*DIMC + lhi*8;
    bf16x8 b0 = *(const bf16x8*)(wrow +   0);
    bf16x8 b1 = *(const bf16x8*)(wrow +  32);
    bf16x8 b2 = *(const bf16x8*)(wrow +  64);
    bf16x8 b3 = *(const bf16x8*)(wrow +  96);
    bf16x8 b4 = *(const bf16x8*)(wrow + 128);
    bf16x8 b5 = *(const bf16x8*)(wrow + 160);
    float bn = pb[s*16 + llo];
    #pragma unroll
    for (int rt = 0; rt < 4; ++rt) {
      int arow = rt*16 + llo;
      f32x4 acc = {0.f,0.f,0.f,0.f};
      acc = mfma16(*(const bf16x8*)(qkb + arow*768 + ((  0 + lhi*16) ^ ((arow&7)<<4))), b0, acc);
      acc = mfma16(*(const bf16x8*)(qkb + arow*768 + (( 64 + lhi*16) ^ ((arow&7)<<4))), b1, acc);
      acc = mfma16(*(const bf16x8*)(qkb + arow*768 + ((128 + lhi*16) ^ ((arow&7)<<4))), b2, acc);
      acc = mfma16(*(const bf16x8*)(qkb + arow*768 + ((192 + lhi*16) ^ ((arow&7)<<4))), b3, acc);
      acc = mfma16(*(const bf16x8*)(qkb + arow*768 + ((256 + lhi*16) ^ ((arow&7)<<4))), b4, acc);
      acc = mfma16(*(const bf16x8*)(qkb + arow*768 + ((320 + lhi*16) ^ ((arow&7)<<4))), b5, acc);
      #pragma unroll
      for (int i = 0; i < 4; ++i) {
        int row = rt*16 + lhi*4 + i;
        if (row < NSEQ)
          out[((size_t)win*NSEQ + row)*DIMC + s*16 + llo] = acc[i] + bn;
      }
    }
  }
}

extern "C" void kernel_launch(void* const* d_in, const int* in_sizes, int n_in,
                              void* d_out, int out_size, void* d_ws, size_t ws_size,
                              hipStream_t stream) {
  const float* x      = (const float*)d_in[0];
  const float* mask   = (const float*)d_in[1];
  const float* qkv_w  = (const float*)d_in[2];
  const float* qkv_b  = (const float*)d_in[3];
  const float* proj_w = (const float*)d_in[4];
  const float* proj_b = (const float*)d_in[5];
  const float* table  = (const float*)d_in[6];
  const int*   ridx   = (const int*)d_in[7];
  float* out = (float*)d_out;
  char* ws = (char*)d_ws;

  const int prep_total = 576*192 + 192*192 + NHEAD*NN + 576 + 192;
  prep_kernel<<<(prep_total + 255)/256, 256, 0, stream>>>(qkv_w, qkv_b, proj_w, proj_b, table, ridx, ws);
  wattn_kernel<<<NBLK, 384, 0, stream>>>(x, mask, ws, out);
}